// Round 15
// baseline (87.474 us; speedup 1.0000x reference)
//
#include <hip/hip_runtime.h>
#include <math.h>

#define KOLD 128
#define KNEW 100
#define GPB  8          // row-groups (16 rows) per block

typedef float f32x4 __attribute__((ext_vector_type(4)));   // native vec for nt-store

// LDS (bytes): 0: tmp_i 101 i32; 512: tmp_t 101 f32;
// 1024: F table = 4 waves x 4 rows x 105 dwords (420 B rows; stride ≡1 mod 4
// dwords -> row r occupies the residue-r bank lattice => all 32 banks used)
#define FT_OFF  1024
#define ROW_B   420
#define WAVE_B  (4 * ROW_B)
#define LDS_BYTES (FT_OFF + 4 * WAVE_B)

// ---- DPP 32-lane inclusive scan (pure VALU; validated R11-R14) ----
template <int CTRL, int ROWM>
__device__ __forceinline__ float dpp_add(float v) {
    int s = __builtin_amdgcn_update_dpp(0, __float_as_int(v), CTRL, ROWM, 0xf, true);
    return v + __int_as_float(s);
}
__device__ __forceinline__ float scan32(float v) {
    v = dpp_add<0x111, 0xf>(v);   // row_shr:1
    v = dpp_add<0x112, 0xf>(v);   // row_shr:2
    v = dpp_add<0x114, 0xf>(v);   // row_shr:4
    v = dpp_add<0x118, 0xf>(v);   // row_shr:8
    v = dpp_add<0x142, 0xa>(v);   // row_bcast:15 into rows 1,3
    return v;
}
__device__ __forceinline__ float grp_total(float scanned, int half) {
    int t0 = __builtin_amdgcn_readlane(__float_as_int(scanned), 31);
    int t1 = __builtin_amdgcn_readlane(__float_as_int(scanned), 63);
    return __int_as_float(half ? t1 : t0);
}

__launch_bounds__(256, 8)
__global__ void rebin_k(const float* __restrict__ logits,
                        const float* __restrict__ oe,
                        const float* __restrict__ ne,
                        float* __restrict__ out, int nrows)
{
    __shared__ __align__(16) char lds[LDS_BYTES];
    int*   tmp_i = (int*)(lds + 0);
    float* tmp_t = (float*)(lds + 512);

    const int tid  = threadIdx.x;
    const int lane = tid & 63;
    const int wid  = tid >> 6;
    const int c    = lane & 31;    // column-quad: owns old bins 4c..4c+3
    const int half = lane >> 5;

    // ---- edge tables (once per block; amortized over GPB groups)
    if (tid <= KNEW) {
        float e = ne[tid];
        int i = 0;
#pragma unroll
        for (int st = 64; st >= 1; st >>= 1) {
            int cand = i + st;
            if (cand <= KOLD - 1 && oe[cand] <= e) i = cand;
        }
        float a = oe[i], b = oe[i + 1];
        float tt = (e - a) / (b - a);
        tmp_i[tid] = i;
        tmp_t[tid] = fminf(fmaxf(tt, 0.f), 1.f);
    }
    __syncthreads();

    // ---- per-lane edge meta in REGISTERS (row-independent, once per block)
    int k0 = 0;
#pragma unroll
    for (int st = 64; st >= 1; st >>= 1) {
        int cand = k0 + st;
        if (cand <= KNEW + 1 && tmp_i[cand - 1] < 4 * c) k0 = cand;
    }
    unsigned kb[4];   // byte offset of F slot (102*4 = pad dump for invalid)
    float    te[4];   // fractional t
    int      se[4];   // bin select 0..3
#pragma unroll
    for (int e = 0; e < 4; ++e) {
        int k  = k0 + e;
        int kc = k <= KNEW ? k : KNEW;
        int ib = tmp_i[kc];
        bool ok = (k <= KNEW) && (ib < 4 * c + 4);
        kb[e] = ok ? (unsigned)(k * 4) : 102u * 4u;
        te[e] = ok ? tmp_t[kc] : 0.f;
        se[e] = ok ? (ib - 4 * c) : 0;
    }

    char* fW = lds + FT_OFF + wid * WAVE_B;
    const int nm1 = nrows - 1;
    const int ngroups = (nrows + 15) >> 4;
    const int gmax = ngroups - 1;
    const float tiny = 1.1754943508222875e-38f;
    const int grp0 = blockIdx.x * GPB;

    // ---- prologue: depth-2 pipeline — load groups grp0, grp0+1 (clamped)
    float4 vA, vB, wA, wB;
    {
        const int g0 = grp0 <= gmax ? grp0 : gmax;
        const int w0 = g0 * 16 + wid * 4;
        vA = *(const float4*)(logits + (size_t)min(w0 + half, nm1) * KOLD + c * 4);
        vB = *(const float4*)(logits + (size_t)min(w0 + 2 + half, nm1) * KOLD + c * 4);
        const int g1 = (grp0 + 1) <= gmax ? (grp0 + 1) : gmax;
        const int w1 = g1 * 16 + wid * 4;
        wA = *(const float4*)(logits + (size_t)min(w1 + half, nm1) * KOLD + c * 4);
        wB = *(const float4*)(logits + (size_t)min(w1 + 2 + half, nm1) * KOLD + c * 4);
    }

#pragma unroll 1
    for (int kg = 0; kg < GPB; ++kg) {
        const int grp = grp0 + kg;
        if (grp >= ngroups) break;
        const int wrow0 = grp * 16 + wid * 4;

        // ---- prefetch group kg+2 (4 KB/wave in flight across the iteration)
        float4 nA, nB;
        {
            const int gn = (grp + 2) <= gmax ? (grp + 2) : gmax;
            const int wn = gn * 16 + wid * 4;
            nA = *(const float4*)(logits + (size_t)min(wn + half, nm1) * KOLD + c * 4);
            nB = *(const float4*)(logits + (size_t)min(wn + 2 + half, nm1) * KOLD + c * 4);
        }

        // ---- chunk A: exp (no max-stab; clamp guard), scan, F writes
        {
            const float e0 = __expf(fminf(fmaxf(vA.x, -80.f), 80.f));
            const float e1 = __expf(fminf(fmaxf(vA.y, -80.f), 80.f));
            const float e2 = __expf(fminf(fmaxf(vA.z, -80.f), 80.f));
            const float e3 = __expf(fminf(fmaxf(vA.w, -80.f), 80.f));
            const float sl = (e0 + e1) + (e2 + e3);
            const float ic = scan32(sl);
            const float tot = grp_total(ic, half);
            float rc = __builtin_amdgcn_rcpf(tot);
            const float inv = rc * (2.0f - tot * rc);
            const float p0 = ic - sl;
            const float p1 = p0 + e0, p2 = p1 + e1, p3 = p2 + e2;
            char* frow = fW + half * ROW_B;
#pragma unroll
            for (int e = 0; e < 4; ++e) {
                const float f0 = fmaf(te[e], e0, p0);
                const float f1 = fmaf(te[e], e1, p1);
                const float f2 = fmaf(te[e], e2, p2);
                const float f3 = fmaf(te[e], e3, p3);
                const float g01 = (se[e] & 1) ? f1 : f0;
                const float g23 = (se[e] & 1) ? f3 : f2;
                const float F   = (se[e] & 2) ? g23 : g01;
                *(float*)(frow + kb[e]) = F * inv;
            }
        }
        // ---- chunk B
        {
            const float e0 = __expf(fminf(fmaxf(vB.x, -80.f), 80.f));
            const float e1 = __expf(fminf(fmaxf(vB.y, -80.f), 80.f));
            const float e2 = __expf(fminf(fmaxf(vB.z, -80.f), 80.f));
            const float e3 = __expf(fminf(fmaxf(vB.w, -80.f), 80.f));
            const float sl = (e0 + e1) + (e2 + e3);
            const float ic = scan32(sl);
            const float tot = grp_total(ic, half);
            float rc = __builtin_amdgcn_rcpf(tot);
            const float inv = rc * (2.0f - tot * rc);
            const float p0 = ic - sl;
            const float p1 = p0 + e0, p2 = p1 + e1, p3 = p2 + e2;
            char* frow = fW + (2 + half) * ROW_B;
#pragma unroll
            for (int e = 0; e < 4; ++e) {
                const float f0 = fmaf(te[e], e0, p0);
                const float f1 = fmaf(te[e], e1, p1);
                const float f2 = fmaf(te[e], e2, p2);
                const float f3 = fmaf(te[e], e3, p3);
                const float g01 = (se[e] & 1) ? f1 : f0;
                const float g23 = (se[e] & 1) ? f3 : f2;
                const float F   = (se[e] & 2) ? g23 : g01;
                *(float*)(frow + kb[e]) = F * inv;
            }
        }
        asm volatile("s_waitcnt lgkmcnt(0)" ::: "memory");  // wave-local F ready

        // ---- phase 2: 400 outputs = 100 tasks of 4 consecutive cols.
        // 5x b32 reads (4B align legal at odd row stride; banks fully spread)
        float* gout = out + (size_t)wrow0 * KNEW;
#pragma unroll
        for (int it = 0; it < 2; ++it) {
            const int t  = it * 64 + lane;
            const int tc = t < 100 ? t : 99;
            const int r  = (tc * 41) >> 10;        // exact /25 for tc < 100
            const int q  = tc - r * 25;
            const float* fp = (const float*)(fW + r * ROW_B) + q * 4;
            const float F0 = fp[0];
            const float F1 = fp[1];
            const float F2 = fp[2];
            const float F3 = fp[3];
            const float F4 = fp[4];
            f32x4 o;
            o.x = __logf(fmaxf(F1 - F0, 0.f) + tiny);
            o.y = __logf(fmaxf(F2 - F1, 0.f) + tiny);
            o.z = __logf(fmaxf(F3 - F2, 0.f) + tiny);
            o.w = __logf(fmaxf(F4 - F3, 0.f) + tiny);
            if (t < 100 && wrow0 + r < nrows) {
                // non-temporal: output never re-read; keep L3 for the input
                __builtin_nontemporal_store(o, (f32x4*)(gout + r * KNEW + q * 4));
            }
        }
        asm volatile("" ::: "memory");   // order reads before next iter's F writes

        vA = wA; vB = wB; wA = nA; wB = nB;
    }
}

extern "C" void kernel_launch(void* const* d_in, const int* in_sizes, int n_in,
                              void* d_out, int out_size, void* d_ws, size_t ws_size,
                              hipStream_t stream) {
    const float* logits = (const float*)d_in[0];
    const float* oe     = (const float*)d_in[1];
    const float* ne     = (const float*)d_in[2];
    float* out          = (float*)d_out;
    const int nrows     = in_sizes[0] / KOLD;

    const int ngroups = (nrows + 15) / 16;
    const int blocks  = (ngroups + GPB - 1) / GPB;   // 128 rows per block
    rebin_k<<<blocks, 256, 0, stream>>>(logits, oe, ne, out, nrows);
}

// Round 16
// 83.197 us; speedup vs baseline: 1.0514x; 1.0514x over previous
//
#include <hip/hip_runtime.h>
#include <math.h>

#define KOLD 128
#define KNEW 100
#define GPB  8          // row-groups (16 rows) per block

typedef float f32x4 __attribute__((ext_vector_type(4)));   // native vec for nt-store

// LDS (bytes): 0: tmp_i 101 i32; 512: tmp_t 101 f32;
// 1024: F table = 4 waves x 4 rows x 127 dwords (508 B rows).
// F slot for edge k: slot(k) = k + (k>>2)  (stride-5 per task) ->
// task q reads slots {5q..5q+3, 5q+5}; 5q mod 32 covers 25 distinct banks
// (gcd(5,32)=1) => <=2 lanes/bank across the wave = conflict-free (m136).
// Dword 126 of each row = dump slot for invalid edge writes.
#define FT_OFF  1024
#define ROW_B   508
#define WAVE_B  (4 * ROW_B)
#define LDS_BYTES (FT_OFF + 4 * WAVE_B)

// ---- DPP 32-lane inclusive scan (pure VALU; validated R11-R15) ----
template <int CTRL, int ROWM>
__device__ __forceinline__ float dpp_add(float v) {
    int s = __builtin_amdgcn_update_dpp(0, __float_as_int(v), CTRL, ROWM, 0xf, true);
    return v + __int_as_float(s);
}
__device__ __forceinline__ float scan32(float v) {
    v = dpp_add<0x111, 0xf>(v);   // row_shr:1
    v = dpp_add<0x112, 0xf>(v);   // row_shr:2
    v = dpp_add<0x114, 0xf>(v);   // row_shr:4
    v = dpp_add<0x118, 0xf>(v);   // row_shr:8
    v = dpp_add<0x142, 0xa>(v);   // row_bcast:15 into rows 1,3
    return v;
}
__device__ __forceinline__ float grp_total(float scanned, int half) {
    int t0 = __builtin_amdgcn_readlane(__float_as_int(scanned), 31);
    int t1 = __builtin_amdgcn_readlane(__float_as_int(scanned), 63);
    return __int_as_float(half ? t1 : t0);
}

__launch_bounds__(256, 8)
__global__ void rebin_k(const float* __restrict__ logits,
                        const float* __restrict__ oe,
                        const float* __restrict__ ne,
                        float* __restrict__ out, int nrows)
{
    __shared__ __align__(16) char lds[LDS_BYTES];
    int*   tmp_i = (int*)(lds + 0);
    float* tmp_t = (float*)(lds + 512);

    const int tid  = threadIdx.x;
    const int lane = tid & 63;
    const int wid  = tid >> 6;
    const int c    = lane & 31;    // column-quad: owns old bins 4c..4c+3
    const int half = lane >> 5;

    // ---- edge tables (once per block; amortized over GPB groups)
    if (tid <= KNEW) {
        float e = ne[tid];
        int i = 0;
#pragma unroll
        for (int st = 64; st >= 1; st >>= 1) {
            int cand = i + st;
            if (cand <= KOLD - 1 && oe[cand] <= e) i = cand;
        }
        float a = oe[i], b = oe[i + 1];
        float tt = (e - a) / (b - a);
        tmp_i[tid] = i;
        tmp_t[tid] = fminf(fmaxf(tt, 0.f), 1.f);
    }
    __syncthreads();

    // ---- per-lane edge meta in REGISTERS (row-independent, once per block)
    int k0 = 0;
#pragma unroll
    for (int st = 64; st >= 1; st >>= 1) {
        int cand = k0 + st;
        if (cand <= KNEW + 1 && tmp_i[cand - 1] < 4 * c) k0 = cand;
    }
    unsigned kb[4];   // byte offset of F slot (dword 126 = dump for invalid)
    float    te[4];   // fractional t
    int      se[4];   // bin select 0..3
#pragma unroll
    for (int e = 0; e < 4; ++e) {
        int k  = k0 + e;
        int kc = k <= KNEW ? k : KNEW;
        int ib = tmp_i[kc];
        bool ok = (k <= KNEW) && (ib < 4 * c + 4);
        kb[e] = ok ? (unsigned)((k + (k >> 2)) * 4) : 126u * 4u;   // slot swizzle
        te[e] = ok ? tmp_t[kc] : 0.f;
        se[e] = ok ? (ib - 4 * c) : 0;
    }

    char* fW = lds + FT_OFF + wid * WAVE_B;
    const int nm1 = nrows - 1;
    const int ngroups = (nrows + 15) >> 4;
    const int gmax = ngroups - 1;
    const float tiny = 1.1754943508222875e-38f;
    const int grp0 = blockIdx.x * GPB;

    // ---- prologue: load group grp0 (clamped); depth-1 pipeline (R14 config)
    float4 vA, vB;
    {
        const int g  = grp0 <= gmax ? grp0 : gmax;
        const int w0 = g * 16 + wid * 4;
        vA = *(const float4*)(logits + (size_t)min(w0 + half, nm1) * KOLD + c * 4);
        vB = *(const float4*)(logits + (size_t)min(w0 + 2 + half, nm1) * KOLD + c * 4);
    }

#pragma unroll 1
    for (int kg = 0; kg < GPB; ++kg) {
        const int grp = grp0 + kg;
        if (grp >= ngroups) break;
        const int wrow0 = grp * 16 + wid * 4;

        // ---- prefetch NEXT group's chunk (in flight across this iteration)
        float4 nA, nB;
        {
            const int gn = (grp + 1) <= gmax ? (grp + 1) : gmax;
            const int wn = gn * 16 + wid * 4;
            nA = *(const float4*)(logits + (size_t)min(wn + half, nm1) * KOLD + c * 4);
            nB = *(const float4*)(logits + (size_t)min(wn + 2 + half, nm1) * KOLD + c * 4);
        }

        // ---- chunk A: exp (no max-stab; clamp guard), scan, F writes
        {
            const float e0 = __expf(fminf(fmaxf(vA.x, -80.f), 80.f));
            const float e1 = __expf(fminf(fmaxf(vA.y, -80.f), 80.f));
            const float e2 = __expf(fminf(fmaxf(vA.z, -80.f), 80.f));
            const float e3 = __expf(fminf(fmaxf(vA.w, -80.f), 80.f));
            const float sl = (e0 + e1) + (e2 + e3);
            const float ic = scan32(sl);
            const float tot = grp_total(ic, half);
            float rc = __builtin_amdgcn_rcpf(tot);
            const float inv = rc * (2.0f - tot * rc);
            const float p0 = ic - sl;
            const float p1 = p0 + e0, p2 = p1 + e1, p3 = p2 + e2;
            char* frow = fW + half * ROW_B;
#pragma unroll
            for (int e = 0; e < 4; ++e) {
                const float f0 = fmaf(te[e], e0, p0);
                const float f1 = fmaf(te[e], e1, p1);
                const float f2 = fmaf(te[e], e2, p2);
                const float f3 = fmaf(te[e], e3, p3);
                const float g01 = (se[e] & 1) ? f1 : f0;
                const float g23 = (se[e] & 1) ? f3 : f2;
                const float F   = (se[e] & 2) ? g23 : g01;
                *(float*)(frow + kb[e]) = F * inv;
            }
        }
        // ---- chunk B
        {
            const float e0 = __expf(fminf(fmaxf(vB.x, -80.f), 80.f));
            const float e1 = __expf(fminf(fmaxf(vB.y, -80.f), 80.f));
            const float e2 = __expf(fminf(fmaxf(vB.z, -80.f), 80.f));
            const float e3 = __expf(fminf(fmaxf(vB.w, -80.f), 80.f));
            const float sl = (e0 + e1) + (e2 + e3);
            const float ic = scan32(sl);
            const float tot = grp_total(ic, half);
            float rc = __builtin_amdgcn_rcpf(tot);
            const float inv = rc * (2.0f - tot * rc);
            const float p0 = ic - sl;
            const float p1 = p0 + e0, p2 = p1 + e1, p3 = p2 + e2;
            char* frow = fW + (2 + half) * ROW_B;
#pragma unroll
            for (int e = 0; e < 4; ++e) {
                const float f0 = fmaf(te[e], e0, p0);
                const float f1 = fmaf(te[e], e1, p1);
                const float f2 = fmaf(te[e], e2, p2);
                const float f3 = fmaf(te[e], e3, p3);
                const float g01 = (se[e] & 1) ? f1 : f0;
                const float g23 = (se[e] & 1) ? f3 : f2;
                const float F   = (se[e] & 2) ? g23 : g01;
                *(float*)(frow + kb[e]) = F * inv;
            }
        }
        asm volatile("s_waitcnt lgkmcnt(0)" ::: "memory");  // wave-local F ready

        // ---- phase 2: 100 tasks x 4 outputs; slots {5q..5q+3, 5q+5}
        float* gout = out + (size_t)wrow0 * KNEW;
#pragma unroll
        for (int it = 0; it < 2; ++it) {
            const int t  = it * 64 + lane;
            const int tc = t < 100 ? t : 99;
            const int r  = (tc * 41) >> 10;        // exact /25 for tc < 100
            const int q  = tc - r * 25;
            const float* fp = (const float*)(fW + r * ROW_B) + q * 5;
            const float F0 = fp[0];
            const float F1 = fp[1];
            const float F2 = fp[2];
            const float F3 = fp[3];
            const float F4 = fp[5];
            f32x4 o;
            o.x = __logf(fmaxf(F1 - F0, 0.f) + tiny);
            o.y = __logf(fmaxf(F2 - F1, 0.f) + tiny);
            o.z = __logf(fmaxf(F3 - F2, 0.f) + tiny);
            o.w = __logf(fmaxf(F4 - F3, 0.f) + tiny);
            if (t < 100 && wrow0 + r < nrows) {
                // non-temporal: output never re-read; keep L3 for the input
                __builtin_nontemporal_store(o, (f32x4*)(gout + r * KNEW + q * 4));
            }
        }
        asm volatile("" ::: "memory");   // order reads before next iter's F writes

        vA = nA; vB = nB;
    }
}

extern "C" void kernel_launch(void* const* d_in, const int* in_sizes, int n_in,
                              void* d_out, int out_size, void* d_ws, size_t ws_size,
                              hipStream_t stream) {
    const float* logits = (const float*)d_in[0];
    const float* oe     = (const float*)d_in[1];
    const float* ne     = (const float*)d_in[2];
    float* out          = (float*)d_out;
    const int nrows     = in_sizes[0] / KOLD;

    const int ngroups = (nrows + 15) / 16;
    const int blocks  = (ngroups + GPB - 1) / GPB;   // 128 rows per block
    rebin_k<<<blocks, 256, 0, stream>>>(logits, oe, ne, out, nrows);
}